// Round 1
// baseline (1094.859 us; speedup 1.0000x reference)
//
#include <hip/hip_runtime.h>
#include <hip/hip_bf16.h>
#include <math.h>

// Problem constants
#define BB 8
#define CC 64
#define NN 4096
#define CO 64
#define KK 20
#define SPLIT 8
#define CN (CC*NN)           // 262144
#define EPSV 1e-5
#define NEG_SLOPE 0.2f
#define CNT_TOTAL 655360.0   // B*N*K

// Workspace layout (bytes)
#define OFF_P1   ((size_t)0)                    // B*N*64 f32 = 8388608
#define OFF_P2   ((size_t)8388608)              // 8388608
#define OFF_XX   ((size_t)16777216)             // B*N f32 = 131072
#define OFF_IDX  ((size_t)16908288)             // B*N*20 i32 = 2621440
#define OFF_PVAL ((size_t)19529728)             // B*N*8*20 f32 = 20971520
#define OFF_PIDX ((size_t)40501248)             // 20971520
#define OFF_MAXH ((size_t)61472768)             // 8388608
#define OFF_MINH ((size_t)69861376)             // 8388608
#define OFF_SUMS ((size_t)78249984)             // 128 doubles = 1024

// ---------------- K1: per-point projections p1=(W1-W2)x, p2=W2 x, and xx=|x|^2
__global__ __launch_bounds__(256) void k1_project(
    const float* __restrict__ x, const float* __restrict__ W,
    float* __restrict__ p1, float* __restrict__ p2, float* __restrict__ xx) {
  const int b  = blockIdx.y;
  const int n0 = blockIdx.x * 64;
  const int t  = threadIdx.x;
  const int pos = t & 63, og = t >> 6;
  const int n = n0 + pos;
  const float* xb = x + (size_t)b*CN + n;   // index with c*NN

  float a1[16], a2[16];
#pragma unroll
  for (int i = 0; i < 16; ++i) { a1[i] = 0.f; a2[i] = 0.f; }
  float xxa = 0.f;

#pragma unroll
  for (int c4 = 0; c4 < 16; ++c4) {
    float xv[4];
#pragma unroll
    for (int u = 0; u < 4; ++u) xv[u] = xb[(size_t)(c4*4+u)*NN];
    if (og == 0) xxa += xv[0]*xv[0] + xv[1]*xv[1] + xv[2]*xv[2] + xv[3]*xv[3];
#pragma unroll
    for (int oi = 0; oi < 16; ++oi) {
      const int o = og*16 + oi;
      const float4 w1 = *(const float4*)(W + o*128 + c4*4);
      const float4 w2 = *(const float4*)(W + o*128 + 64 + c4*4);
      a1[oi] += (w1.x - w2.x)*xv[0] + (w1.y - w2.y)*xv[1]
              + (w1.z - w2.z)*xv[2] + (w1.w - w2.w)*xv[3];
      a2[oi] += w2.x*xv[0] + w2.y*xv[1] + w2.z*xv[2] + w2.w*xv[3];
    }
  }
  float* p1o = p1 + ((size_t)(b*NN + n))*64 + og*16;
  float* p2o = p2 + ((size_t)(b*NN + n))*64 + og*16;
#pragma unroll
  for (int oi = 0; oi < 16; ++oi) { p1o[oi] = a1[oi]; p2o[oi] = a2[oi]; }
  if (og == 0) xx[b*NN + n] = xxa;
}

// ---------------- K2a: pairwise distances + per-thread top-20 over a j-stripe
__global__ __launch_bounds__(256) void k2_dist(
    const float* __restrict__ x, const float* __restrict__ xx,
    float* __restrict__ pval, int* __restrict__ pidx) {
  __shared__ float xjt[128*68];   // [jj][c], padded stride 68 (16B-aligned rows)
  __shared__ float xxj[128];
  const int b = blockIdx.z;
  const int s = blockIdx.y;
  const int t = threadIdx.x;
  const int i = blockIdx.x*256 + t;
  const float* xb = x + (size_t)b*CN;

  // own row into registers (coalesced: lanes i consecutive for each c)
  float4 xi[16];
#pragma unroll
  for (int c4 = 0; c4 < 16; ++c4) {
    xi[c4].x = xb[(size_t)(c4*4+0)*NN + i];
    xi[c4].y = xb[(size_t)(c4*4+1)*NN + i];
    xi[c4].z = xb[(size_t)(c4*4+2)*NN + i];
    xi[c4].w = xb[(size_t)(c4*4+3)*NN + i];
  }
  const float xxi = xx[b*NN + i];

  float tv[KK]; int ti[KK];
#pragma unroll
  for (int k = 0; k < KK; ++k) { tv[k] = -INFINITY; ti[k] = -1; }
  float vmin = -INFINITY; int minslot = 0;

  for (int tile = 0; tile < 4; ++tile) {
    const int j0 = s*512 + tile*128;
    __syncthreads();
#pragma unroll
    for (int r = 0; r < 32; ++r) {
      const int linear = r*256 + t;
      const int c  = linear >> 7;
      const int jj = linear & 127;
      xjt[jj*68 + c] = xb[(size_t)c*NN + j0 + jj];
    }
    if (t < 128) xxj[t] = xx[b*NN + j0 + t];
    __syncthreads();

    for (int jj = 0; jj < 128; ++jj) {
      const float4* row = (const float4*)(xjt + jj*68);  // uniform -> LDS broadcast
      float acc0 = 0.f, acc1 = 0.f, acc2 = 0.f, acc3 = 0.f;
#pragma unroll
      for (int c4 = 0; c4 < 16; ++c4) {
        const float4 v = row[c4];
        acc0 += xi[c4].x*v.x; acc1 += xi[c4].y*v.y;
        acc2 += xi[c4].z*v.z; acc3 += xi[c4].w*v.w;
      }
      const float d = 2.f*((acc0+acc1)+(acc2+acc3)) - xxi - xxj[jj];
      if (d > vmin) {   // insert (rare): static-index selects only (no scratch)
        const int j = j0 + jj;
#pragma unroll
        for (int q = 0; q < KK; ++q) if (q == minslot) { tv[q] = d; ti[q] = j; }
        vmin = tv[0]; minslot = 0;
#pragma unroll
        for (int q = 1; q < KK; ++q) if (tv[q] < vmin) { vmin = tv[q]; minslot = q; }
      }
    }
  }
  const size_t base = ((size_t)(b*NN + i)*SPLIT + s)*KK;
#pragma unroll
  for (int k = 0; k < KK; ++k) { pval[base+k] = tv[k]; pidx[base+k] = ti[k]; }
}

// ---------------- K2b: merge 8 partial top-20 lists -> final top-20 indices
__global__ __launch_bounds__(256) void k2_merge(
    const float* __restrict__ pval, const int* __restrict__ pidx,
    int* __restrict__ idxo) {
  const int row = blockIdx.x*256 + threadIdx.x;    // 0 .. B*N-1
  float tv[KK]; int ti[KK];
#pragma unroll
  for (int k = 0; k < KK; ++k) { tv[k] = -INFINITY; ti[k] = -1; }
  float vmin = -INFINITY; int minslot = 0;
  const size_t base = (size_t)row * (SPLIT*KK);
  for (int q = 0; q < SPLIT*KK; ++q) {
    const float d = pval[base+q];
    const int   j = pidx[base+q];
    if (d > vmin) {
#pragma unroll
      for (int u = 0; u < KK; ++u) if (u == minslot) { tv[u] = d; ti[u] = j; }
      vmin = tv[0]; minslot = 0;
#pragma unroll
      for (int u = 1; u < KK; ++u) if (tv[u] < vmin) { vmin = tv[u]; minslot = u; }
    }
  }
#pragma unroll
  for (int k = 0; k < KK; ++k) idxo[(size_t)row*KK + k] = ti[k];
}

// ---------------- K3: gather neighbors, per-(b,n,o) max/min of h, BN sums
__global__ __launch_bounds__(256) void k3_gather(
    const float* __restrict__ p1, const float* __restrict__ p2,
    const int* __restrict__ idx, float* __restrict__ maxh,
    float* __restrict__ minh, double* __restrict__ sums) {
  const int t = threadIdx.x;
  const int g = t >> 6, o = t & 63;
  const int pn0 = blockIdx.x*64 + g*16;    // linear (b,n) position base
  float sacc = 0.f, ssacc = 0.f;

  for (int p = 0; p < 16; ++p) {
    const int pn = pn0 + p;
    const int bbase = (pn >> 12) << 12;    // b*N  (N = 4096 = 2^12)
    const float p1v = p1[(size_t)pn*64 + o];
    const int* ip = idx + (size_t)pn*KK;
    float mx = -INFINITY, mn = INFINITY;
#pragma unroll
    for (int k = 0; k < KK; ++k) {
      const int j = ip[k];
      const float p2v = p2[((size_t)(bbase + j))*64 + o];
      const float h = p1v + p2v;
      mx = fmaxf(mx, h); mn = fminf(mn, h);
      sacc += h; ssacc += h*h;
    }
    maxh[(size_t)pn*64 + o] = mx;
    minh[(size_t)pn*64 + o] = mn;
  }

  __shared__ float rs[256], rss[256];
  rs[t] = sacc; rss[t] = ssacc;
  __syncthreads();
  if (t < 64) {
    const double s  = (double)rs[t]  + (double)rs[t+64]  + (double)rs[t+128]  + (double)rs[t+192];
    const double ss = (double)rss[t] + (double)rss[t+64] + (double)rss[t+128] + (double)rss[t+192];
    atomicAdd(&sums[t], s);
    atomicAdd(&sums[64 + t], ss);
  }
}

// ---------------- K4: finalize BN, activation, transpose to (b,o,n)
__global__ __launch_bounds__(256) void k4_out(
    const float* __restrict__ maxh, const float* __restrict__ minh,
    const double* __restrict__ sums, const float* __restrict__ gamma,
    const float* __restrict__ beta, float* __restrict__ out) {
  __shared__ float sc[64], sh[64];
  __shared__ float lmax[64*65], lmin[64*65];
  const int b  = blockIdx.y;
  const int n0 = blockIdx.x * 64;
  const int t  = threadIdx.x;

  if (t < 64) {
    const double mean = sums[t] / CNT_TOTAL;
    const double var  = sums[64 + t] / CNT_TOTAL - mean*mean;
    const float scale = gamma[t] * (float)(1.0 / sqrt(var + EPSV));
    sc[t] = scale;
    sh[t] = beta[t] - (float)mean * scale;
  }
#pragma unroll
  for (int r = 0; r < 16; ++r) {
    const int linear = r*256 + t;
    const int o = linear & 63, pos = linear >> 6;
    const size_t g = ((size_t)(b*NN) + n0 + pos)*64 + o;
    lmax[o*65 + pos] = maxh[g];
    lmin[o*65 + pos] = minh[g];
  }
  __syncthreads();

  const int nn = t & 63;
  const int obase = (t >> 6) * 16;
#pragma unroll
  for (int r = 0; r < 16; ++r) {
    const int o = obase + r;
    const float scale = sc[o], shift = sh[o];
    const float src = (scale >= 0.f) ? lmax[o*65 + nn] : lmin[o*65 + nn];
    float v = scale*src + shift;
    v = (v >= 0.f) ? v : NEG_SLOPE*v;
    out[(size_t)b*CO*NN + (size_t)o*NN + n0 + nn] = v;
  }
}

extern "C" void kernel_launch(void* const* d_in, const int* in_sizes, int n_in,
                              void* d_out, int out_size, void* d_ws, size_t ws_size,
                              hipStream_t stream) {
  const float* x     = (const float*)d_in[0];
  const float* W     = (const float*)d_in[1];
  const float* gamma = (const float*)d_in[2];
  const float* beta  = (const float*)d_in[3];
  float* out = (float*)d_out;
  char* ws = (char*)d_ws;

  float*  p1   = (float*)(ws + OFF_P1);
  float*  p2   = (float*)(ws + OFF_P2);
  float*  xx   = (float*)(ws + OFF_XX);
  int*    idx  = (int*)  (ws + OFF_IDX);
  float*  pval = (float*)(ws + OFF_PVAL);
  int*    pidx = (int*)  (ws + OFF_PIDX);
  float*  maxh = (float*)(ws + OFF_MAXH);
  float*  minh = (float*)(ws + OFF_MINH);
  double* sums = (double*)(ws + OFF_SUMS);

  hipMemsetAsync(sums, 0, 128*sizeof(double), stream);

  k1_project<<<dim3(NN/64, BB), 256, 0, stream>>>(x, W, p1, p2, xx);
  k2_dist  <<<dim3(NN/256, SPLIT, BB), 256, 0, stream>>>(x, xx, pval, pidx);
  k2_merge <<<dim3((BB*NN)/256), 256, 0, stream>>>(pval, pidx, idx);
  k3_gather<<<dim3((BB*NN)/64), 256, 0, stream>>>(p1, p2, idx, maxh, minh, sums);
  k4_out   <<<dim3(NN/64, BB), 256, 0, stream>>>(maxh, minh, sums, gamma, beta, out);
}